// Round 1
// baseline (1514.797 us; speedup 1.0000x reference)
//
#include <hip/hip_runtime.h>

// Problem constants (fixed by setup_inputs)
#define BB 4
#define CC 256
#define CQ 32
#define NN 4096   // H*W = 64*64
#define TQ 32     // query tile per workgroup
#define TM 256    // key/value tile per iteration

// ---------------------------------------------------------------------------
// QKV projection: 1x1 convs == per-position GEMV over C.
// Grid: (N/256, 40, B). Each block handles 8 output channels (group g):
//   groups 0..3  -> q (oc 0..31)   stored ws[0 ..)            as [B][CQ][N]
//   groups 4..7  -> k (oc 0..31)   stored ws[B*CQ*N ..)       as [B][CQ][N]
//   groups 8..39 -> v (oc 0..255)  stored ws[2*B*CQ*N ..)     as [B][C ][N]
// Weight/bias indices are block-uniform -> scalar loads; x loads coalesced.
// ---------------------------------------------------------------------------
__global__ __launch_bounds__(256) void qkv_kernel(
    const float* __restrict__ x,
    const float* __restrict__ wq, const float* __restrict__ bq,
    const float* __restrict__ wk, const float* __restrict__ bk,
    const float* __restrict__ wv, const float* __restrict__ bv,
    float* __restrict__ ws)
{
    const int n   = blockIdx.x * 256 + threadIdx.x;
    const int b   = blockIdx.z;
    const int oc0 = blockIdx.y * 8;

    const float* w; const float* bias; float* outp; int ocl; int cout;
    if (oc0 < CQ)            { w = wq; bias = bq; outp = ws;                 ocl = oc0;        cout = CQ; }
    else if (oc0 < 2*CQ)     { w = wk; bias = bk; outp = ws + BB*CQ*NN;      ocl = oc0 - CQ;   cout = CQ; }
    else                     { w = wv; bias = bv; outp = ws + 2*BB*CQ*NN;    ocl = oc0 - 2*CQ; cout = CC; }

    float acc[8];
#pragma unroll
    for (int j = 0; j < 8; ++j) acc[j] = bias[ocl + j];

    const float* xcol = x + (size_t)b * CC * NN + n;
#pragma unroll 4
    for (int c = 0; c < CC; ++c) {
        float xv = xcol[(size_t)c * NN];
#pragma unroll
        for (int j = 0; j < 8; ++j)
            acc[j] += w[(ocl + j) * CC + c] * xv;
    }

#pragma unroll
    for (int j = 0; j < 8; ++j)
        outp[((size_t)b * cout + (ocl + j)) * NN + n] = acc[j];
}

// ---------------------------------------------------------------------------
// Flash-style attention + residual epilogue.
// Grid: (N/TQ, B), 256 threads.
// Per key-tile of TM=256:
//   phase 1: thread t computes logits s[tq] for key column m0+t (k in regs,
//            q tile broadcast from LDS), writes S[tq][t].
//   phase 2: threads t<32 do row-max + alpha (online softmax rescale factor).
//   phase 3: all threads exponentiate S in place.
//   phase 4: threads t<32 row-sum; ALL threads: acc[tq] = acc*alpha +
//            sum_m S[tq][m] * v[c=t][m]   (float4 LDS broadcasts + float4 v).
// Epilogue: out = gamma * acc/l + x.
// ---------------------------------------------------------------------------
__global__ __launch_bounds__(256) void attn_kernel(
    const float* __restrict__ x, const float* __restrict__ ws,
    const float* __restrict__ gamma, float* __restrict__ out)
{
    __shared__ float qs[CQ * TQ];        // qs[c*TQ + tq], 4 KB
    __shared__ float S[TQ * TM];         // 32 KB score/weight tile
    __shared__ float mArr[TQ], lArr[TQ], alphaArr[TQ];

    const int t  = threadIdx.x;
    const int b  = blockIdx.y;
    const int n0 = blockIdx.x * TQ;

    const float* q = ws;
    const float* k = ws + BB*CQ*NN;
    const float* v = ws + 2*BB*CQ*NN;

    for (int idx = t; idx < CQ*TQ; idx += 256) {
        int c = idx / TQ, tq = idx % TQ;
        qs[idx] = q[((size_t)b*CQ + c) * NN + n0 + tq];
    }
    if (t < TQ) { mArr[t] = -1e30f; lArr[t] = 0.f; }

    float acc[TQ];
#pragma unroll
    for (int i = 0; i < TQ; ++i) acc[i] = 0.f;

    __syncthreads();

    for (int mt = 0; mt < NN / TM; ++mt) {
        const int m0 = mt * TM;

        // ---- phase 1: logits for key column m0+t ----
        float kreg[CQ];
#pragma unroll
        for (int c = 0; c < CQ; ++c)
            kreg[c] = k[((size_t)b*CQ + c) * NN + m0 + t];

        float s[TQ];
#pragma unroll
        for (int i = 0; i < TQ; ++i) s[i] = 0.f;
#pragma unroll
        for (int c = 0; c < CQ; ++c) {
            float kv = kreg[c];
#pragma unroll
            for (int tq = 0; tq < TQ; ++tq)
                s[tq] += qs[c*TQ + tq] * kv;
        }
#pragma unroll
        for (int tq = 0; tq < TQ; ++tq) S[tq*TM + t] = s[tq];
        __syncthreads();

        // ---- phase 2: row max + rescale factor ----
        if (t < TQ) {
            float rm = mArr[t];
            const float* Srow = &S[t*TM];
            for (int j = 0; j < TM; ++j) rm = fmaxf(rm, Srow[j]);
            alphaArr[t] = __expf(mArr[t] - rm);
            mArr[t] = rm;
        }
        __syncthreads();

        // ---- phase 3: exponentiate in place ----
        for (int idx = t; idx < TQ*TM; idx += 256) {
            int tq = idx / TM;
            S[idx] = __expf(S[idx] - mArr[tq]);
        }
        __syncthreads();

        // ---- phase 4: row sums + weighted-V accumulation ----
        if (t < TQ) {
            float rs = 0.f;
            const float* Srow = &S[t*TM];
            for (int j = 0; j < TM; ++j) rs += Srow[j];
            lArr[t] = lArr[t]*alphaArr[t] + rs;
        }
#pragma unroll
        for (int tq = 0; tq < TQ; ++tq) acc[tq] *= alphaArr[tq];

        const float* vrow = v + ((size_t)b*CC + t) * NN + m0;
        for (int tm4 = 0; tm4 < TM/4; ++tm4) {
            float4 v4 = *(const float4*)(vrow + tm4*4);
#pragma unroll
            for (int tq = 0; tq < TQ; ++tq) {
                float4 s4 = *(const float4*)&S[tq*TM + tm4*4];
                acc[tq] += s4.x*v4.x + s4.y*v4.y + s4.z*v4.z + s4.w*v4.w;
            }
        }
        __syncthreads();
    }

    // ---- epilogue: out = gamma * (acc/l) + x, channel c = t ----
    const float g = gamma[0];
    const float* xrow = x   + ((size_t)b*CC + t) * NN + n0;
    float*       orow = out + ((size_t)b*CC + t) * NN + n0;
#pragma unroll
    for (int tq = 0; tq < TQ; ++tq)
        orow[tq] = g * (acc[tq] / lArr[tq]) + xrow[tq];
}

extern "C" void kernel_launch(void* const* d_in, const int* in_sizes, int n_in,
                              void* d_out, int out_size, void* d_ws, size_t ws_size,
                              hipStream_t stream) {
    const float* x     = (const float*)d_in[0];
    const float* wq    = (const float*)d_in[1];
    const float* bq    = (const float*)d_in[2];
    const float* wk    = (const float*)d_in[3];
    const float* bk    = (const float*)d_in[4];
    const float* wv    = (const float*)d_in[5];
    const float* bv    = (const float*)d_in[6];
    const float* gamma = (const float*)d_in[7];
    float* out = (float*)d_out;
    float* ws  = (float*)d_ws;   // needs (2*B*CQ*N + B*C*N) floats = 20 MB

    dim3 g1(NN/256, 40, BB);
    qkv_kernel<<<g1, 256, 0, stream>>>(x, wq, bq, wk, bk, wv, bv, ws);

    dim3 g2(NN/TQ, BB);
    attn_kernel<<<g2, 256, 0, stream>>>(x, ws, gamma, out);
}

// Round 2
// 285.388 us; speedup vs baseline: 5.3078x; 5.3078x over previous
//
#include <hip/hip_runtime.h>

// Problem constants (fixed by setup_inputs)
#define BB 4
#define CC 256
#define CQ 32
#define NN 4096   // H*W
#define TK 64     // key tile per iteration
#define LROW 72   // padded LDS row (64 + 8 bf16 -> 144 B, 2-way bank alias = free)

typedef __attribute__((ext_vector_type(8))) short bf16x8;
typedef __attribute__((ext_vector_type(4))) float f32x4;

__device__ inline unsigned short f2bf(float f) {
    unsigned int u = __float_as_uint(f);
    u += 0x7fffu + ((u >> 16) & 1u);   // round-to-nearest-even
    return (unsigned short)(u >> 16);
}

// ---------------------------------------------------------------------------
// QKV projection (1x1 convs). Outputs bf16 into ws:
//   qT : [B][N][CQ]  (row n contiguous in c -> MFMA A-frag = one 16B load)
//   kT : [B][N][CQ]  (                      -> MFMA B-frag = one 16B load)
//   vT : [B][C][N]   (row c contiguous in m -> V B-frag / LDS stage loads)
// Grid (N/256, 40, B); each block: 8 output channels, weights block-uniform.
// ---------------------------------------------------------------------------
__global__ __launch_bounds__(256) void qkv_kernel(
    const float* __restrict__ x,
    const float* __restrict__ wq, const float* __restrict__ bq,
    const float* __restrict__ wk, const float* __restrict__ bk,
    const float* __restrict__ wv, const float* __restrict__ bv,
    unsigned short* __restrict__ ws)
{
    const int n = blockIdx.x * 256 + threadIdx.x;
    const int b = blockIdx.z;
    const int g = blockIdx.y;

    unsigned short* qT = ws;
    unsigned short* kT = ws + (size_t)BB * NN * CQ;
    unsigned short* vT = ws + 2 * (size_t)BB * NN * CQ;

    const float* w; const float* bias; int ocl; int mode;
    if (g < 4)      { mode = 0; w = wq; bias = bq; ocl = g * 8; }
    else if (g < 8) { mode = 1; w = wk; bias = bk; ocl = (g - 4) * 8; }
    else            { mode = 2; w = wv; bias = bv; ocl = (g - 8) * 8; }

    float acc[8];
#pragma unroll
    for (int j = 0; j < 8; ++j) acc[j] = bias[ocl + j];

    const float* xcol = x + (size_t)b * CC * NN + n;
#pragma unroll 4
    for (int c = 0; c < CC; ++c) {
        float xv = xcol[(size_t)c * NN];
#pragma unroll
        for (int j = 0; j < 8; ++j)
            acc[j] += w[(ocl + j) * CC + c] * xv;
    }

    if (mode < 2) {
        unsigned short* dst = (mode == 0 ? qT : kT) + ((size_t)(b * NN + n)) * CQ + ocl;
        bf16x8 pk;
#pragma unroll
        for (int j = 0; j < 8; ++j) pk[j] = (short)f2bf(acc[j]);
        *(bf16x8*)dst = pk;                       // 16B store, ocl multiple of 8
    } else {
#pragma unroll
        for (int j = 0; j < 8; ++j)
            vT[((size_t)(b * CC + ocl + j)) * NN + n] = f2bf(acc[j]);  // coalesced in n
    }
}

// ---------------------------------------------------------------------------
// MFMA flash attention + residual epilogue.
// Grid (N/64, B), 256 threads = 4 waves; wave w owns q-rows n0+w*16 .. +15.
// Per 64-key tile:
//   QK:  4x mfma_f32_16x16x32_bf16 (K=32 == Cq, one MFMA per key subtile)
//   softmax: in-register online softmax; row stats live in the 16-lane
//            column group (C-layout row = quad*4+i), shfl_xor reductions
//   P:   C-layout -> A-layout transpose via per-wave padded LDS tile
//   PV:  2 k-steps x 16 channel-tiles = 32 MFMAs into fp32 C-frags (64 VGPR)
// V tile (32 KB) staged in LDS (shared by 4 waves), double-buffered through
// registers: next tile's global loads issue right after the barrier and are
// only waited on at next iteration's ds_write.
// ---------------------------------------------------------------------------
__global__ __launch_bounds__(256, 1) void attn_kernel(
    const float* __restrict__ x, const unsigned short* __restrict__ ws,
    const float* __restrict__ gamma, float* __restrict__ out)
{
    __shared__ __align__(16) unsigned short Vt[CC][LROW];      // 36,864 B
    __shared__ __align__(16) unsigned short Ps[4][16][LROW];   //  9,216 B

    const int t    = threadIdx.x;
    const int w    = t >> 6;
    const int l    = t & 63;
    const int quad = l >> 4;
    const int lc   = l & 15;
    const int b    = blockIdx.y;
    const int n0   = blockIdx.x * 64;

    const unsigned short* qT = ws;
    const unsigned short* kT = ws + (size_t)BB * NN * CQ;
    const unsigned short* vT = ws + 2 * (size_t)BB * NN * CQ;
    const unsigned short* vbase = vT + (size_t)b * CC * NN;

    // Q A-fragment: A[m=lc][k=quad*8+j], held for the whole kernel
    const bf16x8 aq = *(const bf16x8*)&qT[((size_t)(b * NN + n0 + w * 16 + lc)) * CQ + quad * 8];

    // stage V tile 0 into registers (committed to LDS at loop top)
    f32x4 vreg[8];
#pragma unroll
    for (int j = 0; j < 8; ++j) {
        int chunk = t + 256 * j, c = chunk >> 3, qd = chunk & 7;
        vreg[j] = *(const f32x4*)&vbase[(size_t)c * NN + qd * 8];
    }

    // K B-fragments for tile 0: B[k=c=quad*8+j][n=key=lc]
    bf16x8 bk[4];
#pragma unroll
    for (int sub = 0; sub < 4; ++sub)
        bk[sub] = *(const bf16x8*)&kT[((size_t)(b * NN + sub * 16 + lc)) * CQ + quad * 8];

    f32x4 acc[16];
#pragma unroll
    for (int ct = 0; ct < 16; ++ct) acc[ct] = (f32x4){0.f, 0.f, 0.f, 0.f};
    float mrow[4] = {-1e30f, -1e30f, -1e30f, -1e30f};
    float lrow[4] = {0.f, 0.f, 0.f, 0.f};

    for (int mt = 0; mt < NN / TK; ++mt) {
        // commit staged V tile to LDS
#pragma unroll
        for (int j = 0; j < 8; ++j) {
            int chunk = t + 256 * j, c = chunk >> 3, qd = chunk & 7;
            *(f32x4*)&Vt[c][qd * 8] = vreg[j];
        }
        __syncthreads();

        const int m0n = (mt < NN / TK - 1) ? (mt + 1) * TK : 0;
        // prefetch next V tile (in flight until next iteration's ds_write)
#pragma unroll
        for (int j = 0; j < 8; ++j) {
            int chunk = t + 256 * j, c = chunk >> 3, qd = chunk & 7;
            vreg[j] = *(const f32x4*)&vbase[(size_t)c * NN + m0n + qd * 8];
        }

        // ---- QK^T: S[q=quad*4+i][key=sub*16+lc] ----
        const f32x4 z = {0.f, 0.f, 0.f, 0.f};
        f32x4 s[4];
#pragma unroll
        for (int sub = 0; sub < 4; ++sub)
            s[sub] = __builtin_amdgcn_mfma_f32_16x16x32_bf16(aq, bk[sub], z, 0, 0, 0);

        // prefetch next tile's K fragments
#pragma unroll
        for (int sub = 0; sub < 4; ++sub)
            bk[sub] = *(const bf16x8*)&kT[((size_t)(b * NN + m0n + sub * 16 + lc)) * CQ + quad * 8];

        // ---- online softmax ----
        float alpha[4];
#pragma unroll
        for (int i = 0; i < 4; ++i) {
            float mx = fmaxf(fmaxf(s[0][i], s[1][i]), fmaxf(s[2][i], s[3][i]));
            mx = fmaxf(mx, __shfl_xor(mx, 1));
            mx = fmaxf(mx, __shfl_xor(mx, 2));
            mx = fmaxf(mx, __shfl_xor(mx, 4));
            mx = fmaxf(mx, __shfl_xor(mx, 8));
            float mnew = fmaxf(mrow[i], mx);
            alpha[i] = __expf(mrow[i] - mnew);
            float rs = 0.f;
#pragma unroll
            for (int sub = 0; sub < 4; ++sub) {
                float p = __expf(s[sub][i] - mnew);
                s[sub][i] = p;
                rs += p;
            }
            rs += __shfl_xor(rs, 1);
            rs += __shfl_xor(rs, 2);
            rs += __shfl_xor(rs, 4);
            rs += __shfl_xor(rs, 8);
            lrow[i] = lrow[i] * alpha[i] + rs;
            mrow[i] = mnew;
        }
#pragma unroll
        for (int ct = 0; ct < 16; ++ct)
#pragma unroll
            for (int i = 0; i < 4; ++i) acc[ct][i] *= alpha[i];

        // ---- P: C-layout -> A-layout via per-wave LDS (no barrier needed;
        //      same-wave ds ordering is enforced via lgkmcnt) ----
#pragma unroll
        for (int sub = 0; sub < 4; ++sub)
#pragma unroll
            for (int i = 0; i < 4; ++i)
                Ps[w][quad * 4 + i][sub * 16 + lc] = f2bf(s[sub][i]);

        bf16x8 ap0 = *(const bf16x8*)&Ps[w][lc][quad * 8];
        bf16x8 ap1 = *(const bf16x8*)&Ps[w][lc][32 + quad * 8];

        // ---- PV: acc[ct] += P * V ----
#pragma unroll
        for (int ct = 0; ct < 16; ++ct) {
            bf16x8 bv = *(const bf16x8*)&Vt[ct * 16 + lc][quad * 8];
            acc[ct] = __builtin_amdgcn_mfma_f32_16x16x32_bf16(ap0, bv, acc[ct], 0, 0, 0);
        }
#pragma unroll
        for (int ct = 0; ct < 16; ++ct) {
            bf16x8 bv = *(const bf16x8*)&Vt[ct * 16 + lc][32 + quad * 8];
            acc[ct] = __builtin_amdgcn_mfma_f32_16x16x32_bf16(ap1, bv, acc[ct], 0, 0, 0);
        }
        __syncthreads();   // all Vt reads done before next iteration's ds_write
    }

    // ---- epilogue: out = gamma * acc / l + x ----
    float rl[4];
#pragma unroll
    for (int i = 0; i < 4; ++i) rl[i] = 1.f / lrow[i];
    const float g = gamma[0];
#pragma unroll
    for (int ct = 0; ct < 16; ++ct) {
        int c = ct * 16 + lc;
        size_t base = ((size_t)(b * CC + c)) * NN + n0 + w * 16 + quad * 4;
        f32x4 xr = *(const f32x4*)&x[base];
        f32x4 o;
#pragma unroll
        for (int i = 0; i < 4; ++i) o[i] = g * acc[ct][i] * rl[i] + xr[i];
        *(f32x4*)&out[base] = o;
    }
}

extern "C" void kernel_launch(void* const* d_in, const int* in_sizes, int n_in,
                              void* d_out, int out_size, void* d_ws, size_t ws_size,
                              hipStream_t stream) {
    const float* x     = (const float*)d_in[0];
    const float* wq    = (const float*)d_in[1];
    const float* bq    = (const float*)d_in[2];
    const float* wk    = (const float*)d_in[3];
    const float* bk    = (const float*)d_in[4];
    const float* bv    = (const float*)d_in[6];
    const float* wv    = (const float*)d_in[5];
    const float* gamma = (const float*)d_in[7];
    float* out = (float*)d_out;
    unsigned short* ws = (unsigned short*)d_ws;   // 10 MB bf16 q/k/v

    dim3 g1(NN / 256, 40, BB);
    qkv_kernel<<<g1, 256, 0, stream>>>(x, wq, bq, wk, bk, wv, bv, ws);

    dim3 g2(NN / 64, BB);
    attn_kernel<<<g2, 256, 0, stream>>>(x, ws, gamma, out);
}